// Round 1
// baseline (988.093 us; speedup 1.0000x reference)
//
#include <hip/hip_runtime.h>
#include <hip/hip_bf16.h>
#include <cmath>

#define N_NODES 2000
#define BS 8

__device__ __forceinline__ float elu_f(float v) {
    return v > 0.f ? v : expm1f(v);
}

// ---------------- K1: h1 = x*W1 ; src1/dst1 = h1 . a1 halves ----------------
__global__ __launch_bounds__(256) void prep1_kernel(
    const float* __restrict__ x, const float* __restrict__ W1,
    const float* __restrict__ a1,
    float* __restrict__ h1, float* __restrict__ s1, float* __restrict__ d1) {
    int idx = blockIdx.x * 256 + threadIdx.x;
    if (idx >= BS * N_NODES) return;
    int b = idx / N_NODES, n = idx % N_NODES;
    float xv = x[idx];  // x[b][n][0]
    #pragma unroll
    for (int h = 0; h < 4; ++h) {
        float sr = 0.f, ds = 0.f;
        #pragma unroll
        for (int f = 0; f < 8; ++f) {
            float hv = xv * W1[h * 8 + f];
            h1[(size_t)idx * 32 + h * 8 + f] = hv;
            sr += hv * a1[h * 16 + f];
            ds += hv * a1[h * 16 + 8 + f];
        }
        s1[(b * 4 + h) * N_NODES + n] = sr;
        d1[(b * 4 + h) * N_NODES + n] = ds;
    }
}

// ---------------- K3: h2 = o1 @ W2[h] ; src2/dst2 ----------------
__global__ __launch_bounds__(256) void prep2_kernel(
    const float* __restrict__ o1, const float* __restrict__ W2,
    const float* __restrict__ a2,
    float* __restrict__ h2, float* __restrict__ s2, float* __restrict__ d2) {
    int idx = blockIdx.x * 256 + threadIdx.x;
    if (idx >= BS * N_NODES) return;
    int b = idx / N_NODES, n = idx % N_NODES;
    float in[32];
    #pragma unroll
    for (int k = 0; k < 32; ++k) in[k] = o1[(size_t)idx * 32 + k];
    for (int h = 0; h < 3; ++h) {
        float sr = 0.f, ds = 0.f;
        #pragma unroll
        for (int f = 0; f < 16; ++f) {
            float hv = 0.f;
            #pragma unroll
            for (int k = 0; k < 32; ++k)
                hv += in[k] * W2[h * 512 + k * 16 + f];
            h2[(size_t)idx * 48 + h * 16 + f] = hv;
            sr += hv * a2[h * 32 + f];
            ds += hv * a2[h * 32 + 16 + f];
        }
        s2[(b * 3 + h) * N_NODES + n] = sr;
        d2[(b * 3 + h) * N_NODES + n] = ds;
    }
}

// ---------------- Attention: out[b,i,head*F+f] = elu(softmax_j(mask(lrelu(src_i+dst_j))) @ h) ----
// One wave handles 4 rows; online softmax per lane; butterfly merge.
template <int F, int HF>
__global__ __launch_bounds__(256) void att_kernel(
    const float* __restrict__ adj,
    const float* __restrict__ h,     // [BS][N][HF]
    const float* __restrict__ src,   // [BS*H][N]
    const float* __restrict__ dst,   // [BS*H][N]
    float* __restrict__ out,         // [BS][N][HF]
    int H) {
    const int N = N_NODES;
    int lane = threadIdx.x & 63;
    int wave = threadIdx.x >> 6;
    int head = blockIdx.y;
    int b = blockIdx.z;
    int row0 = blockIdx.x * 16 + wave * 4;

    const float* srcp = src + (size_t)(b * H + head) * N;
    const float* dstp = dst + (size_t)(b * H + head) * N;
    const float* hp = h + (size_t)b * N * HF + head * F;

    float si[4], m[4], s[4];
    float acc[4][F];
    #pragma unroll
    for (int r = 0; r < 4; ++r) {
        si[r] = srcp[row0 + r];
        m[r] = -1e30f;
        s[r] = 0.f;
        #pragma unroll
        for (int f = 0; f < F; ++f) acc[r][f] = 0.f;
    }

    for (int j0 = 0; j0 < N; j0 += 64) {
        int j = j0 + lane;
        bool ok = j < N;
        float dj = ok ? dstp[j] : 0.f;
        float hv[F];
        if (ok) {
            const float4* hj = (const float4*)(hp + (size_t)j * HF);
            #pragma unroll
            for (int q = 0; q < F / 4; ++q) {
                float4 v = hj[q];
                hv[4 * q + 0] = v.x; hv[4 * q + 1] = v.y;
                hv[4 * q + 2] = v.z; hv[4 * q + 3] = v.w;
            }
        } else {
            #pragma unroll
            for (int f = 0; f < F; ++f) hv[f] = 0.f;
        }
        #pragma unroll
        for (int r = 0; r < 4; ++r) {
            float aj = ok ? adj[(size_t)(row0 + r) * N + j] : 0.f;
            float e = si[r] + dj;
            e = e >= 0.f ? e : 0.2f * e;
            e = (aj > 0.f) ? e : -3.0e38f;           // masked -> effectively -inf
            float nm = fmaxf(m[r], e);
            float d = m[r] - e;                       // >=0 means no max update
            float t = __expf(-fabsf(d));              // single exp for both cases
            float sc = (d >= 0.f) ? 1.f : t;          // rescale of old acc
            float p  = (d >= 0.f) ? t : 1.f;          // prob weight of new entry
            s[r] = s[r] * sc + p;
            #pragma unroll
            for (int f = 0; f < F; ++f)
                acc[r][f] = acc[r][f] * sc + p * hv[f];
            m[r] = nm;
        }
    }

    // butterfly merge of (m,s,acc) across 64 lanes
    #pragma unroll
    for (int off = 32; off >= 1; off >>= 1) {
        #pragma unroll
        for (int r = 0; r < 4; ++r) {
            float m2 = __shfl_xor(m[r], off, 64);
            float s2 = __shfl_xor(s[r], off, 64);
            float d = m[r] - m2;
            float t = __expf(-fabsf(d));
            float c1 = (d >= 0.f) ? 1.f : t;
            float c2 = (d >= 0.f) ? t : 1.f;
            s[r] = s[r] * c1 + s2 * c2;
            #pragma unroll
            for (int f = 0; f < F; ++f) {
                float a2v = __shfl_xor(acc[r][f], off, 64);
                acc[r][f] = acc[r][f] * c1 + a2v * c2;
            }
            m[r] = fmaxf(m[r], m2);
        }
    }

    if (lane == 0) {
        #pragma unroll
        for (int r = 0; r < 4; ++r) {
            float inv = s[r] > 0.f ? 1.0f / s[r] : 0.f;
            float* op = out + ((size_t)b * N + row0 + r) * HF + head * F;
            #pragma unroll
            for (int f = 0; f < F; ++f) {
                float v = acc[r][f] * inv;
                op[f] = v > 0.f ? v : expm1f(v);
            }
        }
    }
}

// ---------------- K5: z = [x0 | o1.pw1+pb1 | o2.pw2+pb2] ----------------
__global__ __launch_bounds__(256) void concat_proj_kernel(
    const float* __restrict__ x,
    const float* __restrict__ o1, const float* __restrict__ o2,
    const float* __restrict__ pw1, const float* __restrict__ pb1,
    const float* __restrict__ pw2, const float* __restrict__ pb2,
    float* __restrict__ z) {
    int idx = blockIdx.x * 256 + threadIdx.x;
    if (idx >= BS * N_NODES) return;
    int b = idx / N_NODES, n = idx % N_NODES;
    z[b * 6000 + n] = x[idx];
    float v1 = pb1[0];
    #pragma unroll
    for (int k = 0; k < 32; ++k) v1 += o1[(size_t)idx * 32 + k] * pw1[k];
    z[b * 6000 + 2000 + n] = v1;
    float v2 = pb2[0];
    #pragma unroll
    for (int k = 0; k < 48; ++k) v2 += o2[(size_t)idx * 48 + k] * pw2[k];
    z[b * 6000 + 4000 + n] = v2;
}

// ---------------- Generic FC: out[b,o] = (elu?)(in[b,:] @ W + bias) ----------------
// block = 4 k-slices x 64 o-lanes
__global__ __launch_bounds__(256) void fc_kernel(
    const float* __restrict__ in, const float* __restrict__ W,
    const float* __restrict__ bias, float* __restrict__ out,
    int K, int O, int apply_elu) {
    int b = blockIdx.y;
    int ol = threadIdx.x & 63;
    int o = blockIdx.x * 64 + ol;
    int ks = threadIdx.x >> 6;
    float acc = 0.f;
    if (o < O) {
        for (int k = ks; k < K; k += 4)
            acc += in[(size_t)b * K + k] * W[(size_t)k * O + o];
    }
    __shared__ float red[4][64];
    red[ks][ol] = acc;
    __syncthreads();
    if (ks == 0 && o < O) {
        float v = red[0][ol] + red[1][ol] + red[2][ol] + red[3][ol] + bias[o];
        out[(size_t)b * O + o] = apply_elu ? elu_f(v) : v;
    }
}

extern "C" void kernel_launch(void* const* d_in, const int* in_sizes, int n_in,
                              void* d_out, int out_size, void* d_ws, size_t ws_size,
                              hipStream_t stream) {
    const float* x    = (const float*)d_in[0];
    const float* adj  = (const float*)d_in[1];
    const float* W1   = (const float*)d_in[2];
    const float* a1   = (const float*)d_in[3];
    const float* W2   = (const float*)d_in[4];
    const float* a2   = (const float*)d_in[5];
    const float* pw1  = (const float*)d_in[6];
    const float* pb1  = (const float*)d_in[7];
    const float* pw2  = (const float*)d_in[8];
    const float* pb2  = (const float*)d_in[9];
    const float* fc1w = (const float*)d_in[10];
    const float* fc1b = (const float*)d_in[11];
    const float* fc2w = (const float*)d_in[12];
    const float* fc2b = (const float*)d_in[13];
    const float* fc3w = (const float*)d_in[14];
    const float* fc3b = (const float*)d_in[15];
    const float* fc4w = (const float*)d_in[16];
    const float* fc4b = (const float*)d_in[17];
    const float* fc5w = (const float*)d_in[18];
    const float* fc5b = (const float*)d_in[19];
    float* outp = (float*)d_out;

    float* ws = (float*)d_ws;
    size_t off = 0;
    auto alloc = [&](size_t n) {
        float* p = ws + off;
        off += (n + 63) & ~(size_t)63;
        return p;
    };
    float* h1 = alloc((size_t)BS * N_NODES * 32);
    float* s1 = alloc((size_t)BS * 4 * N_NODES);
    float* d1 = alloc((size_t)BS * 4 * N_NODES);
    float* o1 = alloc((size_t)BS * N_NODES * 32);
    float* h2 = alloc((size_t)BS * N_NODES * 48);
    float* s2 = alloc((size_t)BS * 3 * N_NODES);
    float* d2 = alloc((size_t)BS * 3 * N_NODES);
    float* o2 = alloc((size_t)BS * N_NODES * 48);
    float* z  = alloc((size_t)BS * 6000);
    float* t1 = alloc((size_t)BS * 600);
    float* t2 = alloc((size_t)BS * 256);
    float* t4 = alloc((size_t)BS * 32);

    int nthreads = BS * N_NODES;
    int nblk = (nthreads + 255) / 256;

    prep1_kernel<<<nblk, 256, 0, stream>>>(x, W1, a1, h1, s1, d1);
    att_kernel<8, 32><<<dim3(125, 4, BS), 256, 0, stream>>>(adj, h1, s1, d1, o1, 4);
    prep2_kernel<<<nblk, 256, 0, stream>>>(o1, W2, a2, h2, s2, d2);
    att_kernel<16, 48><<<dim3(125, 3, BS), 256, 0, stream>>>(adj, h2, s2, d2, o2, 3);
    concat_proj_kernel<<<nblk, 256, 0, stream>>>(x, o1, o2, pw1, pb1, pw2, pb2, z);

    fc_kernel<<<dim3(10, BS), 256, 0, stream>>>(z,  fc1w, fc1b, t1, 6000, 600, 1);
    fc_kernel<<<dim3(4,  BS), 256, 0, stream>>>(t1, fc2w, fc2b, t2, 600, 256, 1);
    fc_kernel<<<dim3(1,  BS), 256, 0, stream>>>(t2, fc3w, fc3b, outp, 256, 64, 1);
    fc_kernel<<<dim3(1,  BS), 256, 0, stream>>>(outp, fc4w, fc4b, t4, 64, 32, 1);
    fc_kernel<<<dim3(1,  BS), 256, 0, stream>>>(t4, fc5w, fc5b, outp + (size_t)BS * 64, 32, 2, 0);
}

// Round 2
// 387.375 us; speedup vs baseline: 2.5507x; 2.5507x over previous
//
#include <hip/hip_runtime.h>
#include <hip/hip_bf16.h>
#include <cmath>

#define N_NODES 2000
#define BS 8
#define NW 32  // 64-bit mask words per adjacency row (2000 bits -> 32 words)

__device__ __forceinline__ float elu_f(float v) {
    return v > 0.f ? v : expm1f(v);
}

// ---------------- pack adj row bits: mask[row][w] bit l = adj[row][w*64+l] > 0 ----
__global__ __launch_bounds__(256) void pack_mask_kernel(
    const float* __restrict__ adj, unsigned long long* __restrict__ mask) {
    int row = blockIdx.x;
    int lane = threadIdx.x & 63, wave = threadIdx.x >> 6;
    for (int wq = wave; wq < NW; wq += 4) {
        int j = wq * 64 + lane;
        bool on = (j < N_NODES) && (adj[(size_t)row * N_NODES + j] > 0.f);
        unsigned long long bal = __ballot(on);
        if (lane == 0) mask[(size_t)row * NW + wq] = bal;
    }
}

// ---------------- column max of dst per (b,head) row ----------------
__global__ __launch_bounds__(256) void colmax_kernel(
    const float* __restrict__ dst, float* __restrict__ maxd) {
    int r = blockIdx.x;
    const float* p = dst + (size_t)r * N_NODES;
    float m = -1e30f;
    for (int j = threadIdx.x; j < N_NODES; j += 256) m = fmaxf(m, p[j]);
    __shared__ float red[256];
    red[threadIdx.x] = m;
    __syncthreads();
    for (int s = 128; s > 0; s >>= 1) {
        if (threadIdx.x < s) red[threadIdx.x] = fmaxf(red[threadIdx.x], red[threadIdx.x + s]);
        __syncthreads();
    }
    if (threadIdx.x == 0) maxd[r] = red[0];
}

// ---------------- K1: h1t[b][h][n][8] = x*W1 ; src1/dst1 ----------------
__global__ __launch_bounds__(256) void prep1_kernel(
    const float* __restrict__ x, const float* __restrict__ W1,
    const float* __restrict__ a1,
    float* __restrict__ h1t, float* __restrict__ s1, float* __restrict__ d1) {
    int idx = blockIdx.x * 256 + threadIdx.x;
    if (idx >= BS * N_NODES) return;
    int b = idx / N_NODES, n = idx % N_NODES;
    float xv = x[idx];
    #pragma unroll
    for (int h = 0; h < 4; ++h) {
        float sr = 0.f, ds = 0.f;
        #pragma unroll
        for (int f = 0; f < 8; ++f) {
            float hv = xv * W1[h * 8 + f];
            h1t[((size_t)(b * 4 + h) * N_NODES + n) * 8 + f] = hv;
            sr += hv * a1[h * 16 + f];
            ds += hv * a1[h * 16 + 8 + f];
        }
        s1[(b * 4 + h) * N_NODES + n] = sr;
        d1[(b * 4 + h) * N_NODES + n] = ds;
    }
}

// ---------------- K3: h2t[b][h][n][16] = o1 @ W2[h] ; src2/dst2 ----------------
__global__ __launch_bounds__(256) void prep2_kernel(
    const float* __restrict__ o1, const float* __restrict__ W2,
    const float* __restrict__ a2,
    float* __restrict__ h2t, float* __restrict__ s2, float* __restrict__ d2) {
    int idx = blockIdx.x * 256 + threadIdx.x;
    if (idx >= BS * N_NODES) return;
    int b = idx / N_NODES, n = idx % N_NODES;
    float in[32];
    const float4* ip = (const float4*)(o1 + (size_t)idx * 32);
    #pragma unroll
    for (int q = 0; q < 8; ++q) {
        float4 v = ip[q];
        in[4 * q] = v.x; in[4 * q + 1] = v.y; in[4 * q + 2] = v.z; in[4 * q + 3] = v.w;
    }
    for (int h = 0; h < 3; ++h) {
        float sr = 0.f, ds = 0.f;
        #pragma unroll
        for (int f = 0; f < 16; ++f) {
            float hv = 0.f;
            #pragma unroll
            for (int k = 0; k < 32; ++k)
                hv += in[k] * W2[h * 512 + k * 16 + f];
            h2t[((size_t)(b * 3 + h) * N_NODES + n) * 16 + f] = hv;
            sr += hv * a2[h * 32 + f];
            ds += hv * a2[h * 32 + 16 + f];
        }
        s2[(b * 3 + h) * N_NODES + n] = sr;
        d2[(b * 3 + h) * N_NODES + n] = ds;
    }
}

// ---------------- Attention with bitmask + upper-bound softmax (no online max) ----
// ht: [BS][H][N][F] ; out: [BS][N][HF]
template <int F>
__global__ __launch_bounds__(256) void att_kernel(
    const unsigned long long* __restrict__ mask,
    const float* __restrict__ ht,
    const float* __restrict__ src, const float* __restrict__ dst,
    const float* __restrict__ maxd,
    float* __restrict__ out, int H, int HF) {
    const int N = N_NODES;
    int lane = threadIdx.x & 63;
    int wave = threadIdx.x >> 6;
    int head = blockIdx.y;
    int b = blockIdx.z;
    int row0 = blockIdx.x * 16 + wave * 4;
    int bh = b * H + head;

    const float* srcp = src + (size_t)bh * N;
    const float* dstp = dst + (size_t)bh * N;
    const float* hp = ht + (size_t)bh * N * F;
    float md = maxd[bh];

    float si[4], ub[4], s[4];
    float acc[4][F];
    #pragma unroll
    for (int r = 0; r < 4; ++r) {
        si[r] = srcp[row0 + r];
        float u = si[r] + md;
        ub[r] = fmaxf(u, 0.2f * u);   // lrelu(si + max_dst) >= lrelu(si + dst_j) for all j
        s[r] = 0.f;
        #pragma unroll
        for (int f = 0; f < F; ++f) acc[r][f] = 0.f;
    }

    const unsigned long long lbit = 1ull << lane;

    for (int j0 = 0; j0 < N; j0 += 64) {
        int j = j0 + lane;
        bool ok = j < N;
        float dj = ok ? dstp[j] : -1e30f;
        float hv[F];
        if (ok) {
            const float4* hj = (const float4*)(hp + (size_t)j * F);
            #pragma unroll
            for (int q = 0; q < F / 4; ++q) {
                float4 v = hj[q];
                hv[4 * q + 0] = v.x; hv[4 * q + 1] = v.y;
                hv[4 * q + 2] = v.z; hv[4 * q + 3] = v.w;
            }
        } else {
            #pragma unroll
            for (int f = 0; f < F; ++f) hv[f] = 0.f;
        }
        unsigned long long w[4];
        #pragma unroll
        for (int r = 0; r < 4; ++r) w[r] = mask[(size_t)(row0 + r) * NW + (j0 >> 6)];
        #pragma unroll
        for (int r = 0; r < 4; ++r) {
            float e = si[r] + dj;
            e = fmaxf(e, 0.2f * e);               // leaky relu (slope < 1)
            float p = __expf(e - ub[r]);          // <= 1, no overflow
            p = (w[r] & lbit) ? p : 0.f;
            s[r] += p;
            #pragma unroll
            for (int f = 0; f < F; ++f) acc[r][f] = fmaf(p, hv[f], acc[r][f]);
        }
    }

    // butterfly sum across 64 lanes
    #pragma unroll
    for (int off = 32; off >= 1; off >>= 1) {
        #pragma unroll
        for (int r = 0; r < 4; ++r) {
            s[r] += __shfl_xor(s[r], off, 64);
            #pragma unroll
            for (int f = 0; f < F; ++f) acc[r][f] += __shfl_xor(acc[r][f], off, 64);
        }
    }

    if (lane == 0) {
        #pragma unroll
        for (int r = 0; r < 4; ++r) {
            float inv = s[r] > 0.f ? 1.0f / s[r] : 0.f;
            float* op = out + ((size_t)b * N + row0 + r) * HF + head * F;
            #pragma unroll
            for (int f = 0; f < F; ++f) {
                float v = acc[r][f] * inv;
                op[f] = v > 0.f ? v : expm1f(v);
            }
        }
    }
}

// ---------------- K5: z = [x0 | o1.pw1+pb1 | o2.pw2+pb2] ----------------
__global__ __launch_bounds__(256) void concat_proj_kernel(
    const float* __restrict__ x,
    const float* __restrict__ o1, const float* __restrict__ o2,
    const float* __restrict__ pw1, const float* __restrict__ pb1,
    const float* __restrict__ pw2, const float* __restrict__ pb2,
    float* __restrict__ z) {
    int idx = blockIdx.x * 256 + threadIdx.x;
    if (idx >= BS * N_NODES) return;
    int b = idx / N_NODES, n = idx % N_NODES;
    z[b * 6000 + n] = x[idx];
    float v1 = pb1[0];
    #pragma unroll
    for (int k = 0; k < 32; ++k) v1 += o1[(size_t)idx * 32 + k] * pw1[k];
    z[b * 6000 + 2000 + n] = v1;
    float v2 = pb2[0];
    #pragma unroll
    for (int k = 0; k < 48; ++k) v2 += o2[(size_t)idx * 48 + k] * pw2[k];
    z[b * 6000 + 4000 + n] = v2;
}

// ---------------- batched split-K FC: partial[kt][b][o] ----------------
__global__ __launch_bounds__(256) void fc_splitk_kernel(
    const float* __restrict__ in, const float* __restrict__ W,
    float* __restrict__ partial, int K, int O, int KS) {
    int o = blockIdx.x * 256 + threadIdx.x;
    int kt = blockIdx.y;
    int k0 = kt * KS;
    int k1 = k0 + KS < K ? k0 + KS : K;
    float acc[BS] = {0.f, 0.f, 0.f, 0.f, 0.f, 0.f, 0.f, 0.f};
    if (o < O) {
        for (int k = k0; k < k1; ++k) {
            float w = W[(size_t)k * O + o];
            #pragma unroll
            for (int b = 0; b < BS; ++b) acc[b] = fmaf(in[(size_t)b * K + k], w, acc[b]);
        }
        #pragma unroll
        for (int b = 0; b < BS; ++b)
            partial[((size_t)kt * BS + b) * O + o] = acc[b];
    }
}

__global__ __launch_bounds__(256) void fc_reduce_kernel(
    const float* __restrict__ partial, const float* __restrict__ bias,
    float* __restrict__ out, int O, int KT, int apply_elu) {
    int o = blockIdx.x * 256 + threadIdx.x;
    int b = blockIdx.y;
    if (o >= O) return;
    float a = bias[o];
    for (int kt = 0; kt < KT; ++kt) a += partial[((size_t)kt * BS + b) * O + o];
    out[(size_t)b * O + o] = apply_elu ? elu_f(a) : a;
}

// ---------------- fused fc3 -> fc4 -> fc5 tail (one block per batch) ----------------
__global__ __launch_bounds__(256) void fc_tail_kernel(
    const float* __restrict__ t2,
    const float* __restrict__ w3, const float* __restrict__ b3,
    const float* __restrict__ w4, const float* __restrict__ b4,
    const float* __restrict__ w5, const float* __restrict__ b5,
    float* __restrict__ outp) {
    int b = blockIdx.x;
    __shared__ float z1[64], z4[32], red[256];
    int t = threadIdx.x;
    int o = t & 63, ks = t >> 6;
    float a = 0.f;
    for (int k = ks; k < 256; k += 4) a = fmaf(t2[b * 256 + k], w3[k * 64 + o], a);
    red[t] = a;
    __syncthreads();
    if (ks == 0) {
        float v = red[o] + red[64 + o] + red[128 + o] + red[192 + o] + b3[o];
        v = elu_f(v);
        z1[o] = v;
        outp[b * 64 + o] = v;  // first output (z1)
    }
    __syncthreads();
    if (t < 32) {
        float v = b4[t];
        #pragma unroll
        for (int k = 0; k < 64; ++k) v = fmaf(z1[k], w4[k * 32 + t], v);
        z4[t] = elu_f(v);
    }
    __syncthreads();
    if (t < 2) {
        float v = b5[t];
        #pragma unroll
        for (int k = 0; k < 32; ++k) v = fmaf(z4[k], w5[k * 2 + t], v);
        outp[BS * 64 + b * 2 + t] = v;  // second output (gat_out)
    }
}

extern "C" void kernel_launch(void* const* d_in, const int* in_sizes, int n_in,
                              void* d_out, int out_size, void* d_ws, size_t ws_size,
                              hipStream_t stream) {
    const float* x    = (const float*)d_in[0];
    const float* adj  = (const float*)d_in[1];
    const float* W1   = (const float*)d_in[2];
    const float* a1   = (const float*)d_in[3];
    const float* W2   = (const float*)d_in[4];
    const float* a2   = (const float*)d_in[5];
    const float* pw1  = (const float*)d_in[6];
    const float* pb1  = (const float*)d_in[7];
    const float* pw2  = (const float*)d_in[8];
    const float* pb2  = (const float*)d_in[9];
    const float* fc1w = (const float*)d_in[10];
    const float* fc1b = (const float*)d_in[11];
    const float* fc2w = (const float*)d_in[12];
    const float* fc2b = (const float*)d_in[13];
    const float* fc3w = (const float*)d_in[14];
    const float* fc3b = (const float*)d_in[15];
    const float* fc4w = (const float*)d_in[16];
    const float* fc4b = (const float*)d_in[17];
    const float* fc5w = (const float*)d_in[18];
    const float* fc5b = (const float*)d_in[19];
    float* outp = (float*)d_out;

    float* ws = (float*)d_ws;
    size_t off = 0;
    auto alloc = [&](size_t n) {
        float* p = ws + off;
        off += (n + 63) & ~(size_t)63;
        return p;
    };
    float* h1t = alloc((size_t)BS * 4 * N_NODES * 8 + 512);   // padded for OOB-lane reads
    float* s1  = alloc((size_t)BS * 4 * N_NODES);
    float* d1  = alloc((size_t)BS * 4 * N_NODES + 64);
    float* o1  = alloc((size_t)BS * N_NODES * 32);
    float* h2t = alloc((size_t)BS * 3 * N_NODES * 16 + 1024);
    float* s2  = alloc((size_t)BS * 3 * N_NODES);
    float* d2  = alloc((size_t)BS * 3 * N_NODES + 64);
    float* o2  = alloc((size_t)BS * N_NODES * 48);
    float* z   = alloc((size_t)BS * 6000);
    float* t1  = alloc((size_t)BS * 600);
    float* t2  = alloc((size_t)BS * 256);
    float* md1 = alloc(64);
    float* md2 = alloc(64);
    const int KT1 = 64, KS1 = 94;   // 64*94 = 6016 >= 6000
    const int KT2 = 16, KS2 = 38;   // 16*38 = 608 >= 600
    float* p1  = alloc((size_t)KT1 * BS * 600);
    float* p2  = alloc((size_t)KT2 * BS * 256);
    unsigned long long* mask = (unsigned long long*)alloc((size_t)N_NODES * NW * 2);

    int nthreads = BS * N_NODES;
    int nblk = (nthreads + 255) / 256;

    pack_mask_kernel<<<N_NODES, 256, 0, stream>>>(adj, mask);
    prep1_kernel<<<nblk, 256, 0, stream>>>(x, W1, a1, h1t, s1, d1);
    colmax_kernel<<<BS * 4, 256, 0, stream>>>(d1, md1);
    att_kernel<8><<<dim3(125, 4, BS), 256, 0, stream>>>(mask, h1t, s1, d1, md1, o1, 4, 32);
    prep2_kernel<<<nblk, 256, 0, stream>>>(o1, W2, a2, h2t, s2, d2);
    colmax_kernel<<<BS * 3, 256, 0, stream>>>(d2, md2);
    att_kernel<16><<<dim3(125, 3, BS), 256, 0, stream>>>(mask, h2t, s2, d2, md2, o2, 3, 48);
    concat_proj_kernel<<<nblk, 256, 0, stream>>>(x, o1, o2, pw1, pb1, pw2, pb2, z);

    fc_splitk_kernel<<<dim3(3, KT1), 256, 0, stream>>>(z, fc1w, p1, 6000, 600, KS1);
    fc_reduce_kernel<<<dim3(3, BS), 256, 0, stream>>>(p1, fc1b, t1, 600, KT1, 1);
    fc_splitk_kernel<<<dim3(1, KT2), 256, 0, stream>>>(t1, fc2w, p2, 600, 256, KS2);
    fc_reduce_kernel<<<dim3(1, BS), 256, 0, stream>>>(p2, fc2b, t2, 256, KT2, 1);
    fc_tail_kernel<<<BS, 256, 0, stream>>>(t2, fc3w, fc3b, fc4w, fc4b, fc5w, fc5b, outp);
}

// Round 3
// 229.023 us; speedup vs baseline: 4.3144x; 1.6914x over previous
//
#include <hip/hip_runtime.h>
#include <hip/hip_bf16.h>
#include <cmath>

#define N_NODES 2000
#define BS 8
#define NW 32  // u64 words per adjacency row

typedef __attribute__((ext_vector_type(8))) short short8v;
typedef __attribute__((ext_vector_type(4))) float float4v;

__device__ __forceinline__ float elu_f(float v) { return v > 0.f ? v : expm1f(v); }

__device__ __forceinline__ short f32_bf16(float f) {
    __hip_bfloat16 h = __float2bfloat16(f);
    unsigned short u;
    __builtin_memcpy(&u, &h, 2);
    return (short)u;
}

// ---------------- pack adj row bits ----------------
__global__ __launch_bounds__(256) void pack_mask_kernel(
    const float* __restrict__ adj, unsigned long long* __restrict__ mask) {
    int row = blockIdx.x;
    int lane = threadIdx.x & 63, wv = threadIdx.x >> 6;
    for (int wq = wv; wq < NW; wq += 4) {
        int j = wq * 64 + lane;
        bool on = (j < N_NODES) && (adj[(size_t)row * N_NODES + j] > 0.f);
        unsigned long long bal = __ballot(on);
        if (lane == 0) mask[(size_t)row * NW + wq] = bal;
    }
}

// ---------------- prep1: s1/d1 = x * (W1.a1 halves); xp = padded x ----------------
__global__ __launch_bounds__(256) void prep1_kernel(
    const float* __restrict__ x, const float* __restrict__ W1,
    const float* __restrict__ a1,
    float* __restrict__ xp, float* __restrict__ s1, float* __restrict__ d1) {
    int idx = blockIdx.x * 256 + threadIdx.x;
    if (idx >= BS * N_NODES) return;
    int b = idx / N_NODES, n = idx % N_NODES;
    float xv = x[idx];
    xp[b * 2048 + n] = xv;
    #pragma unroll
    for (int h = 0; h < 4; ++h) {
        float ws_ = 0.f, wd_ = 0.f;
        #pragma unroll
        for (int f = 0; f < 8; ++f) {
            float wv = W1[h * 8 + f];
            ws_ = fmaf(wv, a1[h * 16 + f], ws_);
            wd_ = fmaf(wv, a1[h * 16 + 8 + f], wd_);
        }
        s1[(b * 4 + h) * N_NODES + n] = xv * ws_;
        d1[(b * 4 + h) * N_NODES + n] = xv * wd_;
    }
}

// ---------------- column max over one row of [R][N] ----------------
__global__ __launch_bounds__(256) void colmax_kernel(
    const float* __restrict__ dst, float* __restrict__ maxd) {
    int r = blockIdx.x;
    const float* p = dst + (size_t)r * N_NODES;
    float m = -1e30f;
    for (int j = threadIdx.x; j < N_NODES; j += 256) m = fmaxf(m, p[j]);
    __shared__ float red[256];
    red[threadIdx.x] = m;
    __syncthreads();
    for (int s = 128; s > 0; s >>= 1) {
        if (threadIdx.x < s) red[threadIdx.x] = fmaxf(red[threadIdx.x], red[threadIdx.x + s]);
        __syncthreads();
    }
    if (threadIdx.x == 0) maxd[r] = red[0];
}

// ---------------- rowparams1: P,Q per node; A,B,tP per row (layer1, 32 bh) ------
__global__ __launch_bounds__(256) void rowparams1_kernel(
    const float* __restrict__ s1, const float* __restrict__ d1,
    const float* __restrict__ md1,
    float* __restrict__ P1, float* __restrict__ Q1,
    float* __restrict__ A1, float* __restrict__ B1, float* __restrict__ tP1,
    float* __restrict__ xp) {
    int bh = blockIdx.y;
    int n = blockIdx.x * 256 + threadIdx.x;  // < 2048
    if (n >= N_NODES) {
        P1[bh * 2048 + n] = 0.f;
        Q1[bh * 2048 + n] = 0.f;
        if ((bh & 3) == 0) xp[(bh >> 2) * 2048 + n] = 0.f;
        return;
    }
    float md = md1[bh];
    float d = d1[bh * N_NODES + n];
    P1[bh * 2048 + n] = __expf(d - md);
    Q1[bh * 2048 + n] = __expf(0.2f * (d - md));
    float s = s1[bh * N_NODES + n];
    float u = s + md;
    float ub = fmaxf(u, 0.2f * u);
    A1[bh * N_NODES + n] = __expf(u - ub);
    B1[bh * N_NODES + n] = __expf(0.2f * u - ub);
    tP1[bh * N_NODES + n] = __expf(-u);  // c: s+d>0 <=> P_j > exp(-u)
}

// ---------------- att1: rank-1 layer1 attention, exp-free inner loop ----------------
__global__ __launch_bounds__(256) void att1_kernel(
    const unsigned long long* __restrict__ mask,
    const float* __restrict__ xp,
    const float* __restrict__ P1, const float* __restrict__ Q1,
    const float* __restrict__ A1, const float* __restrict__ B1,
    const float* __restrict__ tP1,
    const float* __restrict__ W1,
    float* __restrict__ o1) {
    int lane = threadIdx.x & 63, wave = threadIdx.x >> 6;
    int head = blockIdx.y, b = blockIdx.z;
    int bh = b * 4 + head;
    int row0 = blockIdx.x * 16 + wave * 4;

    const float* Pp = P1 + (size_t)bh * 2048;
    const float* Qp = Q1 + (size_t)bh * 2048;
    const float* xpp = xp + (size_t)b * 2048;

    float Ar[4], Br[4], tr[4], num[4], den[4];
    #pragma unroll
    for (int r = 0; r < 4; ++r) {
        Ar[r] = A1[bh * N_NODES + row0 + r];
        Br[r] = B1[bh * N_NODES + row0 + r];
        tr[r] = tP1[bh * N_NODES + row0 + r];
        num[r] = 0.f; den[r] = 0.f;
    }
    const unsigned long long lbit = 1ull << lane;

    for (int j0 = 0; j0 < 2048; j0 += 64) {
        int j = j0 + lane;
        float P = Pp[j], Q = Qp[j], xv = xpp[j];
        unsigned long long mw[4];
        #pragma unroll
        for (int r = 0; r < 4; ++r) mw[r] = mask[(size_t)(row0 + r) * NW + (j0 >> 6)];
        #pragma unroll
        for (int r = 0; r < 4; ++r) {
            float w = (P > tr[r]) ? Ar[r] * P : Br[r] * Q;
            w = (mw[r] & lbit) ? w : 0.f;
            num[r] = fmaf(w, xv, num[r]);
            den[r] += w;
        }
    }
    #pragma unroll
    for (int off = 32; off >= 1; off >>= 1) {
        #pragma unroll
        for (int r = 0; r < 4; ++r) {
            num[r] += __shfl_xor(num[r], off, 64);
            den[r] += __shfl_xor(den[r], off, 64);
        }
    }
    if (lane < 8) {
        #pragma unroll
        for (int r = 0; r < 4; ++r) {
            float ratio = den[r] > 0.f ? num[r] / den[r] : 0.f;
            float v = ratio * W1[head * 8 + lane];
            o1[((size_t)b * N_NODES + row0 + r) * 32 + head * 8 + lane] =
                v > 0.f ? v : expm1f(v);
        }
    }
}

// ---------------- prep2: h2 = o1@W2 -> hT (bf16, [bh][f][j]) ; s2/d2 ----------------
__global__ __launch_bounds__(256) void prep2_kernel(
    const float* __restrict__ o1, const float* __restrict__ W2,
    const float* __restrict__ a2,
    short* __restrict__ hT, float* __restrict__ s2, float* __restrict__ d2) {
    int idx = blockIdx.x * 256 + threadIdx.x;
    if (idx >= BS * N_NODES) return;
    int b = idx / N_NODES, n = idx % N_NODES;
    float in[32];
    const float4* ip = (const float4*)(o1 + (size_t)idx * 32);
    #pragma unroll
    for (int q = 0; q < 8; ++q) {
        float4 v = ip[q];
        in[4 * q] = v.x; in[4 * q + 1] = v.y; in[4 * q + 2] = v.z; in[4 * q + 3] = v.w;
    }
    for (int h = 0; h < 3; ++h) {
        float sr = 0.f, ds = 0.f;
        int bh = b * 3 + h;
        #pragma unroll
        for (int f = 0; f < 16; ++f) {
            float hv = 0.f;
            #pragma unroll
            for (int k = 0; k < 32; ++k) hv = fmaf(in[k], W2[h * 512 + k * 16 + f], hv);
            hT[((size_t)bh * 16 + f) * 2016 + n] = f32_bf16(hv);
            sr = fmaf(hv, a2[h * 32 + f], sr);
            ds = fmaf(hv, a2[h * 32 + 16 + f], ds);
        }
        s2[bh * N_NODES + n] = sr;
        d2[bh * N_NODES + n] = ds;
    }
}

// ---------------- rowparams2 (layer2, 24 bh, pads hT) ----------------
__global__ __launch_bounds__(256) void rowparams2_kernel(
    const float* __restrict__ s2, const float* __restrict__ d2,
    const float* __restrict__ md2,
    float* __restrict__ P2, float* __restrict__ Q2,
    float* __restrict__ A2, float* __restrict__ B2, float* __restrict__ tP2,
    short* __restrict__ hT) {
    int bh = blockIdx.y;
    int n = blockIdx.x * 256 + threadIdx.x;
    if (n >= 2016) return;
    if (n >= N_NODES) {
        P2[bh * 2016 + n] = 0.f;
        Q2[bh * 2016 + n] = 0.f;
        #pragma unroll
        for (int f = 0; f < 16; ++f) hT[((size_t)bh * 16 + f) * 2016 + n] = 0;
        return;
    }
    float md = md2[bh];
    float d = d2[bh * N_NODES + n];
    P2[bh * 2016 + n] = __expf(d - md);
    Q2[bh * 2016 + n] = __expf(0.2f * (d - md));
    float s = s2[bh * N_NODES + n];
    float u = s + md;
    float ub = fmaxf(u, 0.2f * u);
    A2[bh * N_NODES + n] = __expf(u - ub);
    B2[bh * N_NODES + n] = __expf(0.2f * u - ub);
    tP2[bh * N_NODES + n] = __expf(-u);
}

// ---------------- att2: layer2 attention via MFMA 16x16x32 bf16 ----------------
// wave handles one 16-row C tile; A = weight tile (16x32), B = hT tile (32x16)
__global__ __launch_bounds__(256) void att2_kernel(
    const unsigned char* __restrict__ mask8,
    const short* __restrict__ hT,
    const float* __restrict__ P2, const float* __restrict__ Q2,
    const float* __restrict__ A2, const float* __restrict__ B2,
    const float* __restrict__ tP2,
    float* __restrict__ o2) {
    int lane = threadIdx.x & 63, wave = threadIdx.x >> 6;
    int t = blockIdx.x * 4 + wave;
    if (t >= 125) return;
    int head = blockIdx.y, b = blockIdx.z;
    int bh = b * 3 + head;
    int rs = lane & 15;      // A row within tile == B col (output feature)
    int g = lane >> 4;       // k-group
    int row = t * 16 + rs;

    float Ar = A2[bh * N_NODES + row];
    float Br = B2[bh * N_NODES + row];
    float tr = tP2[bh * N_NODES + row];
    const float* Pp = P2 + (size_t)bh * 2016;
    const float* Qp = Q2 + (size_t)bh * 2016;
    const short* hb = hT + ((size_t)bh * 16 + rs) * 2016;
    const unsigned char* mrow = mask8 + (size_t)row * (NW * 8);

    float4v acc = {0.f, 0.f, 0.f, 0.f};
    float den = 0.f;

    for (int jc = 0; jc < 63; ++jc) {
        int jb = jc * 32 + g * 8;
        float4 pa = *(const float4*)(Pp + jb);
        float4 pb = *(const float4*)(Pp + jb + 4);
        float4 qa = *(const float4*)(Qp + jb);
        float4 qb = *(const float4*)(Qp + jb + 4);
        unsigned int mb = mrow[jb >> 3];
        float w[8];
        w[0] = (pa.x > tr) ? Ar * pa.x : Br * qa.x;
        w[1] = (pa.y > tr) ? Ar * pa.y : Br * qa.y;
        w[2] = (pa.z > tr) ? Ar * pa.z : Br * qa.z;
        w[3] = (pa.w > tr) ? Ar * pa.w : Br * qa.w;
        w[4] = (pb.x > tr) ? Ar * pb.x : Br * qb.x;
        w[5] = (pb.y > tr) ? Ar * pb.y : Br * qb.y;
        w[6] = (pb.z > tr) ? Ar * pb.z : Br * qb.z;
        w[7] = (pb.w > tr) ? Ar * pb.w : Br * qb.w;
        short8v av;
        #pragma unroll
        for (int e = 0; e < 8; ++e) {
            w[e] = (mb & (1u << e)) ? w[e] : 0.f;
            den += w[e];
            av[e] = f32_bf16(w[e]);
        }
        short8v bv = *(const short8v*)(hb + jb);
        acc = __builtin_amdgcn_mfma_f32_16x16x32_bf16(av, bv, acc, 0, 0, 0);
    }

    den += __shfl_xor(den, 16, 64);
    den += __shfl_xor(den, 32, 64);
    float inv = den > 0.f ? 1.0f / den : 0.f;   // valid for row rs

    #pragma unroll
    for (int reg = 0; reg < 4; ++reg) {
        int crow = g * 4 + reg;                   // C row
        float invr = __shfl(inv, crow, 64);
        float v = acc[reg] * invr;
        v = v > 0.f ? v : expm1f(v);
        o2[((size_t)b * N_NODES + t * 16 + crow) * 48 + head * 16 + rs] = v;
    }
}

// ---------------- concat + scalar projections ----------------
__global__ __launch_bounds__(256) void concat_proj_kernel(
    const float* __restrict__ x,
    const float* __restrict__ o1, const float* __restrict__ o2,
    const float* __restrict__ pw1, const float* __restrict__ pb1,
    const float* __restrict__ pw2, const float* __restrict__ pb2,
    float* __restrict__ z) {
    int idx = blockIdx.x * 256 + threadIdx.x;
    if (idx >= BS * N_NODES) return;
    int b = idx / N_NODES, n = idx % N_NODES;
    z[b * 6000 + n] = x[idx];
    float v1 = pb1[0];
    #pragma unroll
    for (int k = 0; k < 32; ++k) v1 = fmaf(o1[(size_t)idx * 32 + k], pw1[k], v1);
    z[b * 6000 + 2000 + n] = v1;
    float v2 = pb2[0];
    #pragma unroll
    for (int k = 0; k < 48; ++k) v2 = fmaf(o2[(size_t)idx * 48 + k], pw2[k], v2);
    z[b * 6000 + 4000 + n] = v2;
}

// ---------------- batched split-K FC ----------------
__global__ __launch_bounds__(256) void fc_splitk_kernel(
    const float* __restrict__ in, const float* __restrict__ W,
    float* __restrict__ partial, int K, int O, int KS) {
    int o = blockIdx.x * 256 + threadIdx.x;
    int kt = blockIdx.y;
    int k0 = kt * KS;
    int k1 = k0 + KS < K ? k0 + KS : K;
    float acc[BS] = {0.f, 0.f, 0.f, 0.f, 0.f, 0.f, 0.f, 0.f};
    if (o < O) {
        for (int k = k0; k < k1; ++k) {
            float w = W[(size_t)k * O + o];
            #pragma unroll
            for (int b = 0; b < BS; ++b) acc[b] = fmaf(in[(size_t)b * K + k], w, acc[b]);
        }
        #pragma unroll
        for (int b = 0; b < BS; ++b)
            partial[((size_t)kt * BS + b) * O + o] = acc[b];
    }
}

__global__ __launch_bounds__(256) void fc_reduce_kernel(
    const float* __restrict__ partial, const float* __restrict__ bias,
    float* __restrict__ out, int O, int KT, int apply_elu) {
    int o = blockIdx.x * 256 + threadIdx.x;
    int b = blockIdx.y;
    if (o >= O) return;
    float a = bias[o];
    for (int kt = 0; kt < KT; ++kt) a += partial[((size_t)kt * BS + b) * O + o];
    out[(size_t)b * O + o] = apply_elu ? elu_f(a) : a;
}

// ---------------- fused fc3->fc4->fc5 tail ----------------
__global__ __launch_bounds__(256) void fc_tail_kernel(
    const float* __restrict__ t2,
    const float* __restrict__ w3, const float* __restrict__ b3,
    const float* __restrict__ w4, const float* __restrict__ b4,
    const float* __restrict__ w5, const float* __restrict__ b5,
    float* __restrict__ outp) {
    int b = blockIdx.x;
    __shared__ float z1[64], z4[32], red[256];
    int t = threadIdx.x;
    int o = t & 63, ks = t >> 6;
    float a = 0.f;
    for (int k = ks; k < 256; k += 4) a = fmaf(t2[b * 256 + k], w3[k * 64 + o], a);
    red[t] = a;
    __syncthreads();
    if (ks == 0) {
        float v = red[o] + red[64 + o] + red[128 + o] + red[192 + o] + b3[o];
        v = elu_f(v);
        z1[o] = v;
        outp[b * 64 + o] = v;
    }
    __syncthreads();
    if (t < 32) {
        float v = b4[t];
        #pragma unroll
        for (int k = 0; k < 64; ++k) v = fmaf(z1[k], w4[k * 32 + t], v);
        z4[t] = elu_f(v);
    }
    __syncthreads();
    if (t < 2) {
        float v = b5[t];
        #pragma unroll
        for (int k = 0; k < 32; ++k) v = fmaf(z4[k], w5[k * 2 + t], v);
        outp[BS * 64 + b * 2 + t] = v;
    }
}

extern "C" void kernel_launch(void* const* d_in, const int* in_sizes, int n_in,
                              void* d_out, int out_size, void* d_ws, size_t ws_size,
                              hipStream_t stream) {
    const float* x    = (const float*)d_in[0];
    const float* adj  = (const float*)d_in[1];
    const float* W1   = (const float*)d_in[2];
    const float* a1   = (const float*)d_in[3];
    const float* W2   = (const float*)d_in[4];
    const float* a2   = (const float*)d_in[5];
    const float* pw1  = (const float*)d_in[6];
    const float* pb1  = (const float*)d_in[7];
    const float* pw2  = (const float*)d_in[8];
    const float* pb2  = (const float*)d_in[9];
    const float* fc1w = (const float*)d_in[10];
    const float* fc1b = (const float*)d_in[11];
    const float* fc2w = (const float*)d_in[12];
    const float* fc2b = (const float*)d_in[13];
    const float* fc3w = (const float*)d_in[14];
    const float* fc3b = (const float*)d_in[15];
    const float* fc4w = (const float*)d_in[16];
    const float* fc4b = (const float*)d_in[17];
    const float* fc5w = (const float*)d_in[18];
    const float* fc5b = (const float*)d_in[19];
    float* outp = (float*)d_out;

    float* ws = (float*)d_ws;
    size_t off = 0;
    auto alloc = [&](size_t n) {
        float* p = ws + off;
        off += (n + 63) & ~(size_t)63;
        return p;
    };
    float* xp  = alloc((size_t)BS * 2048);
    float* s1  = alloc((size_t)32 * N_NODES);
    float* d1  = alloc((size_t)32 * N_NODES);
    float* P1  = alloc((size_t)32 * 2048);
    float* Q1  = alloc((size_t)32 * 2048);
    float* A1  = alloc((size_t)32 * N_NODES);
    float* B1  = alloc((size_t)32 * N_NODES);
    float* tP1 = alloc((size_t)32 * N_NODES);
    float* md1 = alloc(64);
    float* o1  = alloc((size_t)BS * N_NODES * 32);
    float* s2  = alloc((size_t)24 * N_NODES);
    float* d2  = alloc((size_t)24 * N_NODES);
    float* P2  = alloc((size_t)24 * 2016);
    float* Q2  = alloc((size_t)24 * 2016);
    float* A2  = alloc((size_t)24 * N_NODES);
    float* B2  = alloc((size_t)24 * N_NODES);
    float* tP2 = alloc((size_t)24 * N_NODES);
    float* md2 = alloc(64);
    short* hT  = (short*)alloc((size_t)24 * 16 * 2016 / 2 + 64);
    float* o2  = alloc((size_t)BS * N_NODES * 48);
    float* z   = alloc((size_t)BS * 6000);
    float* t1  = alloc((size_t)BS * 600);
    float* t2  = alloc((size_t)BS * 256);
    const int KT1 = 64, KS1 = 94;
    const int KT2 = 16, KS2 = 38;
    float* p1  = alloc((size_t)KT1 * BS * 600);
    float* p2  = alloc((size_t)KT2 * BS * 256);
    unsigned long long* mask = (unsigned long long*)alloc((size_t)N_NODES * NW * 2);

    int nblk = (BS * N_NODES + 255) / 256;

    pack_mask_kernel<<<N_NODES, 256, 0, stream>>>(adj, mask);
    prep1_kernel<<<nblk, 256, 0, stream>>>(x, W1, a1, xp, s1, d1);
    colmax_kernel<<<32, 256, 0, stream>>>(d1, md1);
    rowparams1_kernel<<<dim3(8, 32), 256, 0, stream>>>(s1, d1, md1, P1, Q1, A1, B1, tP1, xp);
    att1_kernel<<<dim3(125, 4, BS), 256, 0, stream>>>(mask, xp, P1, Q1, A1, B1, tP1, W1, o1);
    prep2_kernel<<<nblk, 256, 0, stream>>>(o1, W2, a2, hT, s2, d2);
    colmax_kernel<<<24, 256, 0, stream>>>(d2, md2);
    rowparams2_kernel<<<dim3(8, 24), 256, 0, stream>>>(s2, d2, md2, P2, Q2, A2, B2, tP2, hT);
    att2_kernel<<<dim3(32, 3, BS), 256, 0, stream>>>(
        (const unsigned char*)mask, hT, P2, Q2, A2, B2, tP2, o2);
    concat_proj_kernel<<<nblk, 256, 0, stream>>>(x, o1, o2, pw1, pb1, pw2, pb2, z);

    fc_splitk_kernel<<<dim3(3, KT1), 256, 0, stream>>>(z, fc1w, p1, 6000, 600, KS1);
    fc_reduce_kernel<<<dim3(3, BS), 256, 0, stream>>>(p1, fc1b, t1, 600, KT1, 1);
    fc_splitk_kernel<<<dim3(1, KT2), 256, 0, stream>>>(t1, fc2w, p2, 600, 256, KS2);
    fc_reduce_kernel<<<dim3(1, BS), 256, 0, stream>>>(p2, fc2b, t2, 256, KT2, 1);
    fc_tail_kernel<<<BS, 256, 0, stream>>>(t2, fc3w, fc3b, fc4w, fc4b, fc5w, fc5b, outp);
}

// Round 4
// 211.401 us; speedup vs baseline: 4.6740x; 1.0834x over previous
//
#include <hip/hip_runtime.h>
#include <hip/hip_bf16.h>
#include <cmath>

#define N_NODES 2000
#define BS 8
#define NW 32  // u64 words per adjacency row

typedef __attribute__((ext_vector_type(8))) short short8v;
typedef __attribute__((ext_vector_type(4))) float float4v;

__device__ __forceinline__ float elu_f(float v) { return v > 0.f ? v : expm1f(v); }

__device__ __forceinline__ short f32_bf16(float f) {
    __hip_bfloat16 h = __float2bfloat16(f);
    unsigned short u;
    __builtin_memcpy(&u, &h, 2);
    return (short)u;
}

// ---------------- pack adj row bits ----------------
__global__ __launch_bounds__(256) void pack_mask_kernel(
    const float* __restrict__ adj, unsigned long long* __restrict__ mask) {
    int row = blockIdx.x;
    int lane = threadIdx.x & 63, wv = threadIdx.x >> 6;
    for (int wq = wv; wq < NW; wq += 4) {
        int j = wq * 64 + lane;
        bool on = (j < N_NODES) && (adj[(size_t)row * N_NODES + j] > 0.f);
        unsigned long long bal = __ballot(on);
        if (lane == 0) mask[(size_t)row * NW + wq] = bal;
    }
}

// ---------------- layer1 params fused: colmax is analytic (d1 = x*wd) ----------------
__global__ __launch_bounds__(256) void l1params_kernel(
    const float* __restrict__ x, const float* __restrict__ W1,
    const float* __restrict__ a1,
    float* __restrict__ P1, float* __restrict__ Q1,
    float* __restrict__ A1, float* __restrict__ B1, float* __restrict__ tP1) {
    int bh = blockIdx.x, b = bh >> 2, h = bh & 3;
    int tid = threadIdx.x;
    float ws = 0.f, wd = 0.f;
    #pragma unroll
    for (int f = 0; f < 8; ++f) {
        float wv = W1[h * 8 + f];
        ws = fmaf(wv, a1[h * 16 + f], ws);
        wd = fmaf(wv, a1[h * 16 + 8 + f], wd);
    }
    float mx = -1e30f, mn = 1e30f;
    for (int n = tid; n < N_NODES; n += 256) {
        float v = x[b * N_NODES + n];
        mx = fmaxf(mx, v); mn = fminf(mn, v);
    }
    __shared__ float rmx[256], rmn[256];
    rmx[tid] = mx; rmn[tid] = mn;
    __syncthreads();
    for (int s = 128; s > 0; s >>= 1) {
        if (tid < s) {
            rmx[tid] = fmaxf(rmx[tid], rmx[tid + s]);
            rmn[tid] = fminf(rmn[tid], rmn[tid + s]);
        }
        __syncthreads();
    }
    float md = wd >= 0.f ? rmx[0] * wd : rmn[0] * wd;  // max_n d1[bh][n]
    for (int n = tid; n < N_NODES; n += 256) {
        float xv = x[b * N_NODES + n];
        float d = xv * wd, s = xv * ws;
        P1[bh * N_NODES + n] = __expf(d - md);
        Q1[bh * N_NODES + n] = __expf(0.2f * (d - md));
        float u = s + md, ub = fmaxf(u, 0.2f * u);
        A1[bh * N_NODES + n] = __expf(u - ub);
        B1[bh * N_NODES + n] = __expf(0.2f * u - ub);
        tP1[bh * N_NODES + n] = __expf(-u);
    }
}

// ---------------- att1: rank-1 layer, 8 rows/wave, LDS-staged P/Q/x ----------------
__global__ __launch_bounds__(256) void att1_kernel(
    const unsigned long long* __restrict__ mask,
    const float* __restrict__ x,
    const float* __restrict__ P1, const float* __restrict__ Q1,
    const float* __restrict__ A1, const float* __restrict__ B1,
    const float* __restrict__ tP1, const float* __restrict__ W1,
    float* __restrict__ o1) {
    __shared__ float sP[2048], sQ[2048], sX[2048];
    int tid = threadIdx.x;
    int head = blockIdx.y, b = blockIdx.z, bh = b * 4 + head;
    const float* Pp = P1 + (size_t)bh * N_NODES;
    const float* Qp = Q1 + (size_t)bh * N_NODES;
    const float* xb = x + (size_t)b * N_NODES;
    for (int i = tid; i < 2048; i += 256) {
        bool ok = i < N_NODES;
        sP[i] = ok ? Pp[i] : 0.f;
        sQ[i] = ok ? Qp[i] : 0.f;
        sX[i] = ok ? xb[i] : 0.f;
    }
    __syncthreads();
    int lane = tid & 63;
    int wave = __builtin_amdgcn_readfirstlane(tid >> 6);
    int t = blockIdx.x * 4 + wave;
    if (t >= 250) return;
    int row0 = t * 8;
    float Ar[8], Br[8], tr[8], num[8], den[8];
    #pragma unroll
    for (int r = 0; r < 8; ++r) {
        Ar[r] = A1[bh * N_NODES + row0 + r];
        Br[r] = B1[bh * N_NODES + row0 + r];
        tr[r] = tP1[bh * N_NODES + row0 + r];
        num[r] = 0.f; den[r] = 0.f;
    }
    const unsigned long long lbit = 1ull << lane;
    for (int j0 = 0; j0 < 2048; j0 += 64) {
        int j = j0 + lane;
        float P = sP[j], Q = sQ[j], xv = sX[j];
        #pragma unroll
        for (int r = 0; r < 8; ++r) {
            unsigned long long mw = mask[(size_t)(row0 + r) * NW + (j0 >> 6)];  // SGPR load
            float w = (P > tr[r]) ? Ar[r] * P : Br[r] * Q;
            w = (mw & lbit) ? w : 0.f;
            num[r] = fmaf(w, xv, num[r]);
            den[r] += w;
        }
    }
    #pragma unroll
    for (int off = 32; off >= 1; off >>= 1) {
        #pragma unroll
        for (int r = 0; r < 8; ++r) {
            num[r] += __shfl_xor(num[r], off, 64);
            den[r] += __shfl_xor(den[r], off, 64);
        }
    }
    if (lane < 8) {
        float wf = W1[head * 8 + lane];
        #pragma unroll
        for (int r = 0; r < 8; ++r) {
            float ratio = den[r] > 0.f ? num[r] / den[r] : 0.f;
            float v = ratio * wf;
            o1[((size_t)(b * N_NODES + row0 + r)) * 32 + head * 8 + lane] =
                v > 0.f ? v : expm1f(v);
        }
    }
}

// ---------------- prep2: thread per (b,h,n); W2 in LDS; hT stride 2048 ----------------
__global__ __launch_bounds__(256) void prep2_kernel(
    const float* __restrict__ o1, const float* __restrict__ W2,
    const float* __restrict__ a2,
    short* __restrict__ hT, float* __restrict__ s2, float* __restrict__ d2) {
    __shared__ float sW[1536];
    int tid = threadIdx.x;
    for (int i = tid; i < 1536; i += 256) sW[i] = W2[i];
    __syncthreads();
    int idx = blockIdx.x * 256 + tid;
    if (idx >= BS * 3 * N_NODES) return;
    int b = idx / 6000, r = idx % 6000, h = r / N_NODES, n = r % N_NODES;
    int bh = b * 3 + h;
    float in[32];
    const float4* ip = (const float4*)(o1 + ((size_t)b * N_NODES + n) * 32);
    #pragma unroll
    for (int q = 0; q < 8; ++q) {
        float4 v = ip[q];
        in[4 * q] = v.x; in[4 * q + 1] = v.y; in[4 * q + 2] = v.z; in[4 * q + 3] = v.w;
    }
    float hv[16];
    #pragma unroll
    for (int f = 0; f < 16; ++f) hv[f] = 0.f;
    #pragma unroll
    for (int k = 0; k < 32; ++k) {
        float ik = in[k];
        #pragma unroll
        for (int f = 0; f < 16; ++f) hv[f] = fmaf(ik, sW[h * 512 + k * 16 + f], hv[f]);
    }
    float sr = 0.f, ds = 0.f;
    #pragma unroll
    for (int f = 0; f < 16; ++f) {
        hT[((size_t)bh * 16 + f) * 2048 + n] = f32_bf16(hv[f]);
        sr = fmaf(hv[f], a2[h * 32 + f], sr);
        ds = fmaf(hv[f], a2[h * 32 + 16 + f], ds);
    }
    s2[bh * N_NODES + n] = sr;
    d2[bh * N_NODES + n] = ds;
}

// ---------------- layer2 params fused (colmax + rowparams + hT pad) ----------------
__global__ __launch_bounds__(256) void l2params_kernel(
    const float* __restrict__ s2, const float* __restrict__ d2,
    float* __restrict__ P2, float* __restrict__ Q2,
    float* __restrict__ A2, float* __restrict__ B2, float* __restrict__ tP2,
    short* __restrict__ hT) {
    int bh = blockIdx.x;
    int tid = threadIdx.x;
    float mx = -1e30f;
    for (int n = tid; n < N_NODES; n += 256) mx = fmaxf(mx, d2[bh * N_NODES + n]);
    __shared__ float rmx[256];
    rmx[tid] = mx;
    __syncthreads();
    for (int s = 128; s > 0; s >>= 1) {
        if (tid < s) rmx[tid] = fmaxf(rmx[tid], rmx[tid + s]);
        __syncthreads();
    }
    float md = rmx[0];
    for (int n = tid; n < N_NODES; n += 256) {
        float d = d2[bh * N_NODES + n];
        P2[bh * N_NODES + n] = __expf(d - md);
        Q2[bh * N_NODES + n] = __expf(0.2f * (d - md));
        float s = s2[bh * N_NODES + n];
        float u = s + md, ub = fmaxf(u, 0.2f * u);
        A2[bh * N_NODES + n] = __expf(u - ub);
        B2[bh * N_NODES + n] = __expf(0.2f * u - ub);
        tP2[bh * N_NODES + n] = __expf(-u);
    }
    // zero hT padding columns [2000,2048)
    for (int i = tid; i < 16 * 48; i += 256) {
        int f = i / 48, n = N_NODES + i % 48;
        hT[((size_t)bh * 16 + f) * 2048 + n] = 0;
    }
}

// ---------------- att2: MFMA 16x16x32, LDS-staged P/Q ----------------
__global__ __launch_bounds__(256) void att2_kernel(
    const unsigned char* __restrict__ mask8,
    const short* __restrict__ hT,
    const float* __restrict__ P2, const float* __restrict__ Q2,
    const float* __restrict__ A2, const float* __restrict__ B2,
    const float* __restrict__ tP2,
    float* __restrict__ o2) {
    __shared__ float sP[2048], sQ[2048];
    int tid = threadIdx.x;
    int head = blockIdx.y, b = blockIdx.z, bh = b * 3 + head;
    const float* Pp = P2 + (size_t)bh * N_NODES;
    const float* Qp = Q2 + (size_t)bh * N_NODES;
    for (int i = tid; i < 2048; i += 256) {
        bool ok = i < N_NODES;
        sP[i] = ok ? Pp[i] : 0.f;
        sQ[i] = ok ? Qp[i] : 0.f;
    }
    __syncthreads();
    int lane = tid & 63;
    int wave = __builtin_amdgcn_readfirstlane(tid >> 6);
    int t = blockIdx.x * 4 + wave;
    if (t >= 125) return;
    int rs = lane & 15;      // A row in tile == C col (feature)
    int g = lane >> 4;       // k-group
    int row = t * 16 + rs;

    float Ar = A2[bh * N_NODES + row];
    float Br = B2[bh * N_NODES + row];
    float tr = tP2[bh * N_NODES + row];
    const short* hb = hT + ((size_t)bh * 16 + rs) * 2048;
    const unsigned char* mrow = mask8 + (size_t)row * 256;

    float4v acc = {0.f, 0.f, 0.f, 0.f};
    float den = 0.f;

    for (int jc = 0; jc < 64; ++jc) {
        int jb = jc * 32 + g * 8;
        float4 pa = *(const float4*)(sP + jb);
        float4 pb = *(const float4*)(sP + jb + 4);
        float4 qa = *(const float4*)(sQ + jb);
        float4 qb = *(const float4*)(sQ + jb + 4);
        unsigned int mb = *(const unsigned int*)(mrow + jc * 4);
        unsigned int mby = mb >> (g * 8);
        float w[8];
        w[0] = (pa.x > tr) ? Ar * pa.x : Br * qa.x;
        w[1] = (pa.y > tr) ? Ar * pa.y : Br * qa.y;
        w[2] = (pa.z > tr) ? Ar * pa.z : Br * qa.z;
        w[3] = (pa.w > tr) ? Ar * pa.w : Br * qa.w;
        w[4] = (pb.x > tr) ? Ar * pb.x : Br * qb.x;
        w[5] = (pb.y > tr) ? Ar * pb.y : Br * qb.y;
        w[6] = (pb.z > tr) ? Ar * pb.z : Br * qb.z;
        w[7] = (pb.w > tr) ? Ar * pb.w : Br * qb.w;
        short8v av;
        #pragma unroll
        for (int e = 0; e < 8; ++e) {
            w[e] = (mby & (1u << e)) ? w[e] : 0.f;
            den += w[e];
            av[e] = f32_bf16(w[e]);
        }
        short8v bv = *(const short8v*)(hb + jb);
        acc = __builtin_amdgcn_mfma_f32_16x16x32_bf16(av, bv, acc, 0, 0, 0);
    }

    den += __shfl_xor(den, 16, 64);
    den += __shfl_xor(den, 32, 64);
    float inv = den > 0.f ? 1.0f / den : 0.f;   // for row rs

    #pragma unroll
    for (int reg = 0; reg < 4; ++reg) {
        int crow = g * 4 + reg;
        float invr = __shfl(inv, crow, 64);
        float v = acc[reg] * invr;
        v = v > 0.f ? v : expm1f(v);
        o2[((size_t)(b * N_NODES + t * 16 + crow)) * 48 + head * 16 + rs] = v;
    }
}

// ---------------- concat + scalar projections ----------------
__global__ __launch_bounds__(256) void concat_proj_kernel(
    const float* __restrict__ x,
    const float* __restrict__ o1, const float* __restrict__ o2,
    const float* __restrict__ pw1, const float* __restrict__ pb1,
    const float* __restrict__ pw2, const float* __restrict__ pb2,
    float* __restrict__ z) {
    int idx = blockIdx.x * 256 + threadIdx.x;
    if (idx >= BS * N_NODES) return;
    int b = idx / N_NODES, n = idx % N_NODES;
    z[b * 6000 + n] = x[idx];
    float v1 = pb1[0];
    #pragma unroll
    for (int k = 0; k < 32; ++k) v1 = fmaf(o1[(size_t)idx * 32 + k], pw1[k], v1);
    z[b * 6000 + 2000 + n] = v1;
    float v2 = pb2[0];
    #pragma unroll
    for (int k = 0; k < 48; ++k) v2 = fmaf(o2[(size_t)idx * 48 + k], pw2[k], v2);
    z[b * 6000 + 4000 + n] = v2;
}

// ---------------- batched split-K FC with LDS-staged activations ----------------
__global__ __launch_bounds__(256) void fc_splitk_kernel(
    const float* __restrict__ in, const float* __restrict__ W,
    float* __restrict__ partial, int K, int O, int KS) {
    __shared__ float sz[BS][96];
    int tid = threadIdx.x;
    int o = blockIdx.x * 256 + tid;
    int kt = blockIdx.y;
    int k0 = kt * KS;
    int k1 = k0 + KS < K ? k0 + KS : K;
    int len = k1 - k0;
    for (int i = tid; i < BS * len; i += 256)
        sz[i / len][i % len] = in[(size_t)(i / len) * K + k0 + i % len];
    __syncthreads();
    float acc[BS] = {0.f, 0.f, 0.f, 0.f, 0.f, 0.f, 0.f, 0.f};
    if (o < O) {
        for (int k = 0; k < len; ++k) {
            float w = W[(size_t)(k0 + k) * O + o];
            #pragma unroll
            for (int b = 0; b < BS; ++b) acc[b] = fmaf(sz[b][k], w, acc[b]);
        }
        #pragma unroll
        for (int b = 0; b < BS; ++b)
            partial[((size_t)kt * BS + b) * O + o] = acc[b];
    }
}

__global__ __launch_bounds__(256) void fc_reduce_kernel(
    const float* __restrict__ partial, const float* __restrict__ bias,
    float* __restrict__ out, int O, int KT, int apply_elu) {
    int o = blockIdx.x * 256 + threadIdx.x;
    int b = blockIdx.y;
    if (o >= O) return;
    float a = bias[o];
    for (int kt = 0; kt < KT; ++kt) a += partial[((size_t)kt * BS + b) * O + o];
    out[(size_t)b * O + o] = apply_elu ? elu_f(a) : a;
}

// ---------------- fused fc3->fc4->fc5 tail ----------------
__global__ __launch_bounds__(256) void fc_tail_kernel(
    const float* __restrict__ t2,
    const float* __restrict__ w3, const float* __restrict__ b3,
    const float* __restrict__ w4, const float* __restrict__ b4,
    const float* __restrict__ w5, const float* __restrict__ b5,
    float* __restrict__ outp) {
    int b = blockIdx.x;
    __shared__ float z1[64], z4[32], red[256];
    int t = threadIdx.x;
    int o = t & 63, ks = t >> 6;
    float a = 0.f;
    for (int k = ks; k < 256; k += 4) a = fmaf(t2[b * 256 + k], w3[k * 64 + o], a);
    red[t] = a;
    __syncthreads();
    if (ks == 0) {
        float v = red[o] + red[64 + o] + red[128 + o] + red[192 + o] + b3[o];
        v = elu_f(v);
        z1[o] = v;
        outp[b * 64 + o] = v;
    }
    __syncthreads();
    if (t < 32) {
        float v = b4[t];
        #pragma unroll
        for (int k = 0; k < 64; ++k) v = fmaf(z1[k], w4[k * 32 + t], v);
        z4[t] = elu_f(v);
    }
    __syncthreads();
    if (t < 2) {
        float v = b5[t];
        #pragma unroll
        for (int k = 0; k < 32; ++k) v = fmaf(z4[k], w5[k * 2 + t], v);
        outp[BS * 64 + b * 2 + t] = v;
    }
}

extern "C" void kernel_launch(void* const* d_in, const int* in_sizes, int n_in,
                              void* d_out, int out_size, void* d_ws, size_t ws_size,
                              hipStream_t stream) {
    const float* x    = (const float*)d_in[0];
    const float* adj  = (const float*)d_in[1];
    const float* W1   = (const float*)d_in[2];
    const float* a1   = (const float*)d_in[3];
    const float* W2   = (const float*)d_in[4];
    const float* a2   = (const float*)d_in[5];
    const float* pw1  = (const float*)d_in[6];
    const float* pb1  = (const float*)d_in[7];
    const float* pw2  = (const float*)d_in[8];
    const float* pb2  = (const float*)d_in[9];
    const float* fc1w = (const float*)d_in[10];
    const float* fc1b = (const float*)d_in[11];
    const float* fc2w = (const float*)d_in[12];
    const float* fc2b = (const float*)d_in[13];
    const float* fc3w = (const float*)d_in[14];
    const float* fc3b = (const float*)d_in[15];
    const float* fc4w = (const float*)d_in[16];
    const float* fc4b = (const float*)d_in[17];
    const float* fc5w = (const float*)d_in[18];
    const float* fc5b = (const float*)d_in[19];
    float* outp = (float*)d_out;

    float* ws = (float*)d_ws;
    size_t off = 0;
    auto alloc = [&](size_t n) {
        float* p = ws + off;
        off += (n + 63) & ~(size_t)63;
        return p;
    };
    float* P1  = alloc((size_t)32 * N_NODES);
    float* Q1  = alloc((size_t)32 * N_NODES);
    float* A1  = alloc((size_t)32 * N_NODES);
    float* B1  = alloc((size_t)32 * N_NODES);
    float* tP1 = alloc((size_t)32 * N_NODES);
    float* o1  = alloc((size_t)BS * N_NODES * 32);
    float* s2  = alloc((size_t)24 * N_NODES);
    float* d2  = alloc((size_t)24 * N_NODES);
    float* P2  = alloc((size_t)24 * N_NODES);
    float* Q2  = alloc((size_t)24 * N_NODES);
    float* A2  = alloc((size_t)24 * N_NODES);
    float* B2  = alloc((size_t)24 * N_NODES);
    float* tP2 = alloc((size_t)24 * N_NODES);
    short* hT  = (short*)alloc((size_t)24 * 16 * 2048 / 2);
    float* o2  = alloc((size_t)BS * N_NODES * 48);
    float* z   = alloc((size_t)BS * 6000);
    float* t1  = alloc((size_t)BS * 600);
    float* t2  = alloc((size_t)BS * 256);
    const int KT1 = 64, KS1 = 94;
    const int KT2 = 16, KS2 = 38;
    float* p1  = alloc((size_t)KT1 * BS * 600);
    float* p2  = alloc((size_t)KT2 * BS * 256);
    unsigned long long* mask = (unsigned long long*)alloc((size_t)N_NODES * NW * 2);

    int nblk = (BS * N_NODES + 255) / 256;

    pack_mask_kernel<<<N_NODES, 256, 0, stream>>>(adj, mask);
    l1params_kernel<<<32, 256, 0, stream>>>(x, W1, a1, P1, Q1, A1, B1, tP1);
    att1_kernel<<<dim3(63, 4, BS), 256, 0, stream>>>(mask, x, P1, Q1, A1, B1, tP1, W1, o1);
    prep2_kernel<<<(BS * 3 * N_NODES + 255) / 256, 256, 0, stream>>>(o1, W2, a2, hT, s2, d2);
    l2params_kernel<<<24, 256, 0, stream>>>(s2, d2, P2, Q2, A2, B2, tP2, hT);
    att2_kernel<<<dim3(32, 3, BS), 256, 0, stream>>>(
        (const unsigned char*)mask, hT, P2, Q2, A2, B2, tP2, o2);
    concat_proj_kernel<<<nblk, 256, 0, stream>>>(x, o1, o2, pw1, pb1, pw2, pb2, z);

    fc_splitk_kernel<<<dim3(3, KT1), 256, 0, stream>>>(z, fc1w, p1, 6000, 600, KS1);
    fc_reduce_kernel<<<dim3(3, BS), 256, 0, stream>>>(p1, fc1b, t1, 600, KT1, 1);
    fc_splitk_kernel<<<dim3(1, KT2), 256, 0, stream>>>(t1, fc2w, p2, 600, 256, KS2);
    fc_reduce_kernel<<<dim3(1, BS), 256, 0, stream>>>(p2, fc2b, t2, 256, KT2, 1);
    fc_tail_kernel<<<BS, 256, 0, stream>>>(t2, fc3w, fc3b, fc4w, fc4b, fc5w, fc5b, outp);
}

// Round 5
// 164.255 us; speedup vs baseline: 6.0156x; 1.2870x over previous
//
#include <hip/hip_runtime.h>
#include <hip/hip_bf16.h>
#include <cmath>

#define N_NODES 2000
#define BS 8
#define NW 32  // u64 words per adjacency row

typedef __attribute__((ext_vector_type(8))) short short8v;
typedef __attribute__((ext_vector_type(4))) float float4v;

__device__ __forceinline__ float elu_f(float v) { return v > 0.f ? v : expm1f(v); }

__device__ __forceinline__ short f32_bf16(float f) {
    __hip_bfloat16 h = __float2bfloat16(f);
    unsigned short u;
    __builtin_memcpy(&u, &h, 2);
    return (short)u;
}

// w = mask_bit(lane) ? w : 0  — uses the wave-uniform 64-bit mask as a lane predicate
__device__ __forceinline__ float sel_mask(float w, unsigned long long m) {
    float r;
    asm("v_cndmask_b32 %0, 0, %1, %2" : "=v"(r) : "v"(w), "s"(m));
    return r;
}

// ---------------- fused: pack adj rows (transposed) + layer1 params ----------------
__global__ __launch_bounds__(256) void pack_l1_kernel(
    const float* __restrict__ adj, const float* __restrict__ x,
    const float* __restrict__ W1, const float* __restrict__ a1,
    unsigned long long* __restrict__ maskT, unsigned int* __restrict__ maskT32,
    float* __restrict__ PQ1, float* __restrict__ A1, float* __restrict__ B1) {
    if (blockIdx.x < N_NODES) {
        int row = blockIdx.x;
        int lane = threadIdx.x & 63, wv = threadIdx.x >> 6;
        for (int w = wv; w < NW; w += 4) {
            int j = w * 64 + lane;
            bool on = (j < N_NODES) && (adj[(size_t)row * N_NODES + j] > 0.f);
            unsigned long long bal = __ballot(on);
            if (lane == 0) {
                maskT[(size_t)w * 2048 + row] = bal;
                maskT32[(size_t)(2 * w) * 2048 + row] = (unsigned int)bal;
                maskT32[(size_t)(2 * w + 1) * 2048 + row] = (unsigned int)(bal >> 32);
            }
        }
        return;
    }
    int bh = blockIdx.x - N_NODES;  // 0..31
    int b = bh >> 2, h = bh & 3;
    int tid = threadIdx.x;
    float ws = 0.f, wd = 0.f;
    #pragma unroll
    for (int f = 0; f < 8; ++f) {
        float wv = W1[h * 8 + f];
        ws = fmaf(wv, a1[h * 16 + f], ws);
        wd = fmaf(wv, a1[h * 16 + 8 + f], wd);
    }
    float mx = -1e30f, mn = 1e30f;
    for (int n = tid; n < N_NODES; n += 256) {
        float v = x[b * N_NODES + n];
        mx = fmaxf(mx, v); mn = fminf(mn, v);
    }
    __shared__ float rmx[256], rmn[256];
    rmx[tid] = mx; rmn[tid] = mn;
    __syncthreads();
    for (int s = 128; s > 0; s >>= 1) {
        if (tid < s) {
            rmx[tid] = fmaxf(rmx[tid], rmx[tid + s]);
            rmn[tid] = fminf(rmn[tid], rmn[tid + s]);
        }
        __syncthreads();
    }
    float md = wd >= 0.f ? rmx[0] * wd : rmn[0] * wd;  // max_n d1[bh][n]
    for (int n = tid; n < 2048; n += 256) {
        if (n < N_NODES) {
            float xv = x[b * N_NODES + n];
            float d = xv * wd, s = xv * ws;
            PQ1[(size_t)bh * 4096 + 2 * n]     = __expf(d - md);
            PQ1[(size_t)bh * 4096 + 2 * n + 1] = __expf(0.2f * (d - md));
            float u = s + md, ub = fmaxf(u, 0.2f * u);
            A1[bh * N_NODES + n] = __expf(u - ub);
            B1[bh * N_NODES + n] = __expf(0.2f * u - ub);
        } else {
            PQ1[(size_t)bh * 4096 + 2 * n] = 0.f;
            PQ1[(size_t)bh * 4096 + 2 * n + 1] = 0.f;
        }
    }
}

// ---------------- att1: rank-1 layer, 8 rows/wave, w = max(A*P, B*Q), vcc masking ----
__global__ __launch_bounds__(256) void att1_kernel(
    const unsigned long long* __restrict__ maskT,
    const float* __restrict__ x,
    const float* __restrict__ PQ1,
    const float* __restrict__ A1, const float* __restrict__ B1,
    const float* __restrict__ W1,
    float* __restrict__ o1) {
    __shared__ float2 sPQ[2048];
    __shared__ float sX[2048];
    int tid = threadIdx.x;
    int head = blockIdx.y, b = blockIdx.z, bh = b * 4 + head;
    const float2* pq = (const float2*)(PQ1 + (size_t)bh * 4096);
    const float* xb = x + (size_t)b * N_NODES;
    for (int i = tid; i < 2048; i += 256) {
        sPQ[i] = pq[i];
        sX[i] = (i < N_NODES) ? xb[i] : 0.f;
    }
    __syncthreads();
    int lane = tid & 63;
    int wave = __builtin_amdgcn_readfirstlane(tid >> 6);
    int t = blockIdx.x * 4 + wave;
    if (t >= 250) return;
    int row0 = t * 8;
    float Ar[8], Br[8], num[8], den[8];
    #pragma unroll
    for (int r = 0; r < 8; ++r) {
        Ar[r] = A1[bh * N_NODES + row0 + r];
        Br[r] = B1[bh * N_NODES + row0 + r];
        num[r] = 0.f; den[r] = 0.f;
    }
    for (int j0 = 0; j0 < 2048; j0 += 64) {
        float2 pqv = sPQ[j0 + lane];
        float xv = sX[j0 + lane];
        const unsigned long long* mrow = maskT + ((size_t)(j0 >> 6) << 11) + row0;
        #pragma unroll
        for (int r = 0; r < 8; ++r) {
            float w = fmaxf(Ar[r] * pqv.x, Br[r] * pqv.y);
            w = sel_mask(w, mrow[r]);
            num[r] = fmaf(w, xv, num[r]);
            den[r] += w;
        }
    }
    #pragma unroll
    for (int off = 32; off >= 1; off >>= 1) {
        #pragma unroll
        for (int r = 0; r < 8; ++r) {
            num[r] += __shfl_xor(num[r], off, 64);
            den[r] += __shfl_xor(den[r], off, 64);
        }
    }
    if (lane < 8) {
        float wf = W1[head * 8 + lane];
        #pragma unroll
        for (int r = 0; r < 8; ++r) {
            float ratio = den[r] > 0.f ? num[r] / den[r] : 0.f;
            float v = ratio * wf;
            o1[((size_t)(b * N_NODES + row0 + r)) * 32 + head * 8 + lane] =
                v > 0.f ? v : expm1f(v);
        }
    }
}

// ---------------- prep2: thread per (b,h,n); W2 in LDS; hT stride 2048 ----------------
__global__ __launch_bounds__(256) void prep2_kernel(
    const float* __restrict__ o1, const float* __restrict__ W2,
    const float* __restrict__ a2,
    short* __restrict__ hT, float* __restrict__ s2, float* __restrict__ d2) {
    __shared__ float sW[1536];
    int tid = threadIdx.x;
    for (int i = tid; i < 1536; i += 256) sW[i] = W2[i];
    __syncthreads();
    int idx = blockIdx.x * 256 + tid;
    if (idx >= BS * 3 * N_NODES) return;
    int b = idx / 6000, r = idx % 6000, h = r / N_NODES, n = r % N_NODES;
    int bh = b * 3 + h;
    float in[32];
    const float4* ip = (const float4*)(o1 + ((size_t)b * N_NODES + n) * 32);
    #pragma unroll
    for (int q = 0; q < 8; ++q) {
        float4 v = ip[q];
        in[4 * q] = v.x; in[4 * q + 1] = v.y; in[4 * q + 2] = v.z; in[4 * q + 3] = v.w;
    }
    float hv[16];
    #pragma unroll
    for (int f = 0; f < 16; ++f) hv[f] = 0.f;
    #pragma unroll
    for (int k = 0; k < 32; ++k) {
        float ik = in[k];
        #pragma unroll
        for (int f = 0; f < 16; ++f) hv[f] = fmaf(ik, sW[h * 512 + k * 16 + f], hv[f]);
    }
    float sr = 0.f, ds = 0.f;
    #pragma unroll
    for (int f = 0; f < 16; ++f) {
        hT[((size_t)bh * 16 + f) * 2048 + n] = f32_bf16(hv[f]);
        sr = fmaf(hv[f], a2[h * 32 + f], sr);
        ds = fmaf(hv[f], a2[h * 32 + 16 + f], ds);
    }
    s2[bh * N_NODES + n] = sr;
    d2[bh * N_NODES + n] = ds;
}

// ---------------- layer2 params (colmax + rowparams + hT pad) ----------------
__global__ __launch_bounds__(256) void l2params_kernel(
    const float* __restrict__ s2, const float* __restrict__ d2,
    float* __restrict__ PQ2, float* __restrict__ A2, float* __restrict__ B2,
    short* __restrict__ hT) {
    int bh = blockIdx.x;
    int tid = threadIdx.x;
    float mx = -1e30f;
    for (int n = tid; n < N_NODES; n += 256) mx = fmaxf(mx, d2[bh * N_NODES + n]);
    __shared__ float rmx[256];
    rmx[tid] = mx;
    __syncthreads();
    for (int s = 128; s > 0; s >>= 1) {
        if (tid < s) rmx[tid] = fmaxf(rmx[tid], rmx[tid + s]);
        __syncthreads();
    }
    float md = rmx[0];
    for (int n = tid; n < 2048; n += 256) {
        if (n < N_NODES) {
            float d = d2[bh * N_NODES + n];
            PQ2[(size_t)bh * 4096 + 2 * n]     = __expf(d - md);
            PQ2[(size_t)bh * 4096 + 2 * n + 1] = __expf(0.2f * (d - md));
            float s = s2[bh * N_NODES + n];
            float u = s + md, ub = fmaxf(u, 0.2f * u);
            A2[bh * N_NODES + n] = __expf(u - ub);
            B2[bh * N_NODES + n] = __expf(0.2f * u - ub);
        } else {
            PQ2[(size_t)bh * 4096 + 2 * n] = 0.f;
            PQ2[(size_t)bh * 4096 + 2 * n + 1] = 0.f;
        }
    }
    for (int i = tid; i < 16 * 48; i += 256) {
        int f = i / 48, n = N_NODES + i % 48;
        hT[((size_t)bh * 16 + f) * 2048 + n] = 0;
    }
}

// ---------------- att2: MFMA 16x16x32, LDS PQ, transposed mask, max-trick ----------------
__global__ __launch_bounds__(256) void att2_kernel(
    const unsigned int* __restrict__ maskT32,
    const short* __restrict__ hT,
    const float* __restrict__ PQ2,
    const float* __restrict__ A2, const float* __restrict__ B2,
    float* __restrict__ o2) {
    __shared__ float2 sPQ[2048];
    int tid = threadIdx.x;
    int head = blockIdx.y, b = blockIdx.z, bh = b * 3 + head;
    const float2* pq = (const float2*)(PQ2 + (size_t)bh * 4096);
    for (int i = tid; i < 2048; i += 256) sPQ[i] = pq[i];
    __syncthreads();
    int lane = tid & 63;
    int wave = __builtin_amdgcn_readfirstlane(tid >> 6);
    int t = blockIdx.x * 4 + wave;
    if (t >= 125) return;
    int rs = lane & 15;      // A row in tile == C col (feature)
    int g = lane >> 4;       // k-group
    int row = t * 16 + rs;

    float Ar = A2[bh * N_NODES + row];
    float Br = B2[bh * N_NODES + row];
    const short* hb = hT + ((size_t)bh * 16 + rs) * 2048;

    float4v acc = {0.f, 0.f, 0.f, 0.f};
    float den = 0.f;

    for (int jc = 0; jc < 64; ++jc) {
        int jb = jc * 32 + g * 8;
        float w[8];
        #pragma unroll
        for (int e2 = 0; e2 < 4; ++e2) {
            float4 pq2 = *(const float4*)(&sPQ[jb + e2 * 2]);  // P0,Q0,P1,Q1
            w[e2 * 2 + 0] = fmaxf(Ar * pq2.x, Br * pq2.y);
            w[e2 * 2 + 1] = fmaxf(Ar * pq2.z, Br * pq2.w);
        }
        unsigned int mby = maskT32[(size_t)jc * 2048 + row] >> (g * 8);
        short8v av;
        #pragma unroll
        for (int e = 0; e < 8; ++e) {
            float we = (mby & (1u << e)) ? w[e] : 0.f;
            den += we;
            av[e] = f32_bf16(we);
        }
        short8v bv = *(const short8v*)(hb + jb);
        acc = __builtin_amdgcn_mfma_f32_16x16x32_bf16(av, bv, acc, 0, 0, 0);
    }

    den += __shfl_xor(den, 16, 64);
    den += __shfl_xor(den, 32, 64);
    float inv = den > 0.f ? 1.0f / den : 0.f;   // for row rs

    #pragma unroll
    for (int reg = 0; reg < 4; ++reg) {
        int crow = g * 4 + reg;
        float invr = __shfl(inv, crow, 64);
        float v = acc[reg] * invr;
        v = v > 0.f ? v : expm1f(v);
        o2[((size_t)(b * N_NODES + t * 16 + crow)) * 48 + head * 16 + rs] = v;
    }
}

// ---------------- fc1 split-K with inline concat/projection staging ----------------
__global__ __launch_bounds__(256) void fc1_splitk_kernel(
    const float* __restrict__ x,
    const float* __restrict__ o1, const float* __restrict__ o2,
    const float* __restrict__ pw1, const float* __restrict__ pb1,
    const float* __restrict__ pw2, const float* __restrict__ pb2,
    const float* __restrict__ W, float* __restrict__ partial) {
    const int K = 6000, O = 600, KS = 94;
    __shared__ float sz[BS][KS];
    int tid = threadIdx.x;
    int kt = blockIdx.y;
    int k0 = kt * KS;
    int len = (k0 + KS < K) ? KS : (K - k0);
    for (int i = tid; i < BS * len; i += 256) {
        int bb = i / len, k = k0 + i % len;
        float v;
        if (k < 2000) {
            v = x[bb * 2000 + k];
        } else if (k < 4000) {
            const float* op = o1 + ((size_t)bb * 2000 + (k - 2000)) * 32;
            float s = pb1[0];
            #pragma unroll
            for (int q = 0; q < 32; ++q) s = fmaf(op[q], pw1[q], s);
            v = s;
        } else {
            const float* op = o2 + ((size_t)bb * 2000 + (k - 4000)) * 48;
            float s = pb2[0];
            #pragma unroll
            for (int q = 0; q < 48; ++q) s = fmaf(op[q], pw2[q], s);
            v = s;
        }
        sz[bb][i % len] = v;
    }
    __syncthreads();
    int o = blockIdx.x * 256 + tid;
    float acc[BS] = {0.f, 0.f, 0.f, 0.f, 0.f, 0.f, 0.f, 0.f};
    if (o < O) {
        for (int k = 0; k < len; ++k) {
            float w = W[(size_t)(k0 + k) * O + o];
            #pragma unroll
            for (int b = 0; b < BS; ++b) acc[b] = fmaf(sz[b][k], w, acc[b]);
        }
        #pragma unroll
        for (int b = 0; b < BS; ++b)
            partial[((size_t)kt * BS + b) * O + o] = acc[b];
    }
}

// ---------------- generic batched split-K FC (fc2) ----------------
__global__ __launch_bounds__(256) void fc_splitk_kernel(
    const float* __restrict__ in, const float* __restrict__ W,
    float* __restrict__ partial, int K, int O, int KS) {
    __shared__ float sz[BS][96];
    int tid = threadIdx.x;
    int o = blockIdx.x * 256 + tid;
    int kt = blockIdx.y;
    int k0 = kt * KS;
    int k1 = k0 + KS < K ? k0 + KS : K;
    int len = k1 - k0;
    for (int i = tid; i < BS * len; i += 256)
        sz[i / len][i % len] = in[(size_t)(i / len) * K + k0 + i % len];
    __syncthreads();
    float acc[BS] = {0.f, 0.f, 0.f, 0.f, 0.f, 0.f, 0.f, 0.f};
    if (o < O) {
        for (int k = 0; k < len; ++k) {
            float w = W[(size_t)(k0 + k) * O + o];
            #pragma unroll
            for (int b = 0; b < BS; ++b) acc[b] = fmaf(sz[b][k], w, acc[b]);
        }
        #pragma unroll
        for (int b = 0; b < BS; ++b)
            partial[((size_t)kt * BS + b) * O + o] = acc[b];
    }
}

__global__ __launch_bounds__(256) void fc_reduce_kernel(
    const float* __restrict__ partial, const float* __restrict__ bias,
    float* __restrict__ out, int O, int KT, int apply_elu) {
    int o = blockIdx.x * 256 + threadIdx.x;
    int b = blockIdx.y;
    if (o >= O) return;
    float a = bias[o];
    for (int kt = 0; kt < KT; ++kt) a += partial[((size_t)kt * BS + b) * O + o];
    out[(size_t)b * O + o] = apply_elu ? elu_f(a) : a;
}

// ---------------- fused fc3->fc4->fc5 tail ----------------
__global__ __launch_bounds__(256) void fc_tail_kernel(
    const float* __restrict__ t2,
    const float* __restrict__ w3, const float* __restrict__ b3,
    const float* __restrict__ w4, const float* __restrict__ b4,
    const float* __restrict__ w5, const float* __restrict__ b5,
    float* __restrict__ outp) {
    int b = blockIdx.x;
    __shared__ float z1[64], z4[32], red[256];
    int t = threadIdx.x;
    int o = t & 63, ks = t >> 6;
    float a = 0.f;
    for (int k = ks; k < 256; k += 4) a = fmaf(t2[b * 256 + k], w3[k * 64 + o], a);
    red[t] = a;
    __syncthreads();
    if (ks == 0) {
        float v = red[o] + red[64 + o] + red[128 + o] + red[192 + o] + b3[o];
        v = elu_f(v);
        z1[o] = v;
        outp[b * 64 + o] = v;
    }
    __syncthreads();
    if (t < 32) {
        float v = b4[t];
        #pragma unroll
        for (int k = 0; k < 64; ++k) v = fmaf(z1[k], w4[k * 32 + t], v);
        z4[t] = elu_f(v);
    }
    __syncthreads();
    if (t < 2) {
        float v = b5[t];
        #pragma unroll
        for (int k = 0; k < 32; ++k) v = fmaf(z4[k], w5[k * 2 + t], v);
        outp[BS * 64 + b * 2 + t] = v;
    }
}

extern "C" void kernel_launch(void* const* d_in, const int* in_sizes, int n_in,
                              void* d_out, int out_size, void* d_ws, size_t ws_size,
                              hipStream_t stream) {
    const float* x    = (const float*)d_in[0];
    const float* adj  = (const float*)d_in[1];
    const float* W1   = (const float*)d_in[2];
    const float* a1   = (const float*)d_in[3];
    const float* W2   = (const float*)d_in[4];
    const float* a2   = (const float*)d_in[5];
    const float* pw1  = (const float*)d_in[6];
    const float* pb1  = (const float*)d_in[7];
    const float* pw2  = (const float*)d_in[8];
    const float* pb2  = (const float*)d_in[9];
    const float* fc1w = (const float*)d_in[10];
    const float* fc1b = (const float*)d_in[11];
    const float* fc2w = (const float*)d_in[12];
    const float* fc2b = (const float*)d_in[13];
    const float* fc3w = (const float*)d_in[14];
    const float* fc3b = (const float*)d_in[15];
    const float* fc4w = (const float*)d_in[16];
    const float* fc4b = (const float*)d_in[17];
    const float* fc5w = (const float*)d_in[18];
    const float* fc5b = (const float*)d_in[19];
    float* outp = (float*)d_out;

    float* ws = (float*)d_ws;
    size_t off = 0;
    auto alloc = [&](size_t n) {
        float* p = ws + off;
        off += (n + 63) & ~(size_t)63;
        return p;
    };
    float* PQ1 = alloc((size_t)32 * 4096);
    float* A1  = alloc((size_t)32 * N_NODES);
    float* B1  = alloc((size_t)32 * N_NODES);
    float* o1  = alloc((size_t)BS * N_NODES * 32);
    float* s2  = alloc((size_t)24 * N_NODES);
    float* d2  = alloc((size_t)24 * N_NODES);
    float* PQ2 = alloc((size_t)24 * 4096);
    float* A2  = alloc((size_t)24 * N_NODES);
    float* B2  = alloc((size_t)24 * N_NODES);
    short* hT  = (short*)alloc((size_t)24 * 16 * 2048 / 2);
    float* o2  = alloc((size_t)BS * N_NODES * 48);
    float* t1  = alloc((size_t)BS * 600);
    float* t2  = alloc((size_t)BS * 256);
    const int KT1 = 64;
    const int KT2 = 16, KS2 = 38;
    float* p1  = alloc((size_t)KT1 * BS * 600);
    float* p2  = alloc((size_t)KT2 * BS * 256);
    unsigned long long* maskT = (unsigned long long*)alloc((size_t)NW * 2048 * 2);
    unsigned int* maskT32 = (unsigned int*)alloc((size_t)64 * 2048);

    pack_l1_kernel<<<N_NODES + 32, 256, 0, stream>>>(
        adj, x, W1, a1, maskT, maskT32, PQ1, A1, B1);
    att1_kernel<<<dim3(63, 4, BS), 256, 0, stream>>>(maskT, x, PQ1, A1, B1, W1, o1);
    prep2_kernel<<<(BS * 3 * N_NODES + 255) / 256, 256, 0, stream>>>(o1, W2, a2, hT, s2, d2);
    l2params_kernel<<<24, 256, 0, stream>>>(s2, d2, PQ2, A2, B2, hT);
    att2_kernel<<<dim3(32, 3, BS), 256, 0, stream>>>(maskT32, hT, PQ2, A2, B2, o2);

    fc1_splitk_kernel<<<dim3(3, KT1), 256, 0, stream>>>(
        x, o1, o2, pw1, pb1, pw2, pb2, fc1w, p1);
    fc_reduce_kernel<<<dim3(3, BS), 256, 0, stream>>>(p1, fc1b, t1, 600, KT1, 1);
    fc_splitk_kernel<<<dim3(1, KT2), 256, 0, stream>>>(t1, fc2w, p2, 600, 256, KS2);
    fc_reduce_kernel<<<dim3(1, BS), 256, 0, stream>>>(p2, fc2b, t2, 256, KT2, 1);
    fc_tail_kernel<<<BS, 256, 0, stream>>>(t2, fc3w, fc3b, fc4w, fc4b, fc5w, fc5b, outp);
}